// Round 5
// baseline (284.262 us; speedup 1.0000x reference)
//
#include <hip/hip_runtime.h>
#include <math.h>

#define NEG_INF -1000000000.0f

// ---------------------------------------------------------------------------
// Precompute kernel: blocks 0..63 -> posc[s][j] = (pos MLP @ w_pos) + att_b1
//                    blocks 64..191 -> tgtc[b][j] = target_emb[b] @ w_tgt
// posc folds att_b1 so the main kernel's accumulator init is just posc+tgtc.
// ---------------------------------------------------------------------------
__global__ __launch_bounds__(64) void doe_pre_kernel(
    const float* __restrict__ pos_w1, const float* __restrict__ pos_b1,
    const float* __restrict__ pos_w2, const float* __restrict__ pos_b2,
    const float* __restrict__ att_w1, const float* __restrict__ att_b1,
    const float* __restrict__ target_emb,
    float* __restrict__ posc, float* __restrict__ tgtc)
{
    const int tid = threadIdx.x;
    if (blockIdx.x < 64) {
        const int s = blockIdx.x;
        __shared__ float p1[64];
        __shared__ float pe[64];
        float pos = (float)s * (1.0f / 63.0f);
        p1[tid] = fmaxf(fmaf(pos, pos_w1[tid], pos_b1[tid]), 0.0f);
        __syncthreads();
        float acc = pos_b2[tid];
        #pragma unroll
        for (int h = 0; h < 64; ++h) acc = fmaf(p1[h], pos_w2[h * 64 + tid], acc);
        pe[tid] = acc;
        __syncthreads();
        float pc = att_b1[tid];
        #pragma unroll
        for (int h = 0; h < 64; ++h) pc = fmaf(pe[h], att_w1[(64 + h) * 64 + tid], pc);
        posc[s * 64 + tid] = pc;
    } else {
        const int b = blockIdx.x - 64;
        const float* trow = target_emb + b * 64;   // wave-uniform -> s_load
        float acc = 0.0f;
        #pragma unroll
        for (int d = 0; d < 64; ++d) acc = fmaf(trow[d], att_w1[(128 + d) * 64 + tid], acc);
        tgtc[b * 64 + tid] = acc;
    }
}

// ---------------------------------------------------------------------------
// Main fused kernel: one wave per (b,t) tile; 4 waves (tiles) per block.
// Phases: stage tile->LDS (swizzled) | GEMM+bias+relu+score (lane<->s) |
//         wave softmax | weighted sum (lane<->d) | proj | layernorm | store
// LDS: 4*16KiB tiles + 2*256B scratch = ~66 KiB -> 2 blocks/CU = 8 waves/CU
// ---------------------------------------------------------------------------
__global__ __launch_bounds__(256, 2) void doe_main_kernel(
    const float* __restrict__ seg_emb, const int* __restrict__ smask,
    const float* __restrict__ att_w1, const float* __restrict__ att_w2,
    const float* __restrict__ att_b2, const float* __restrict__ proj_w,
    const float* __restrict__ proj_b, const float* __restrict__ ln_g,
    const float* __restrict__ ln_b, const float* __restrict__ posc,
    const float* __restrict__ tgtc, float* __restrict__ out)
{
    __shared__ float tile[4][4096];
    __shared__ float attn_s[4][64];
    __shared__ float segv_s[4][64];

    const int w    = threadIdx.x >> 6;
    const int lane = threadIdx.x & 63;
    const int g    = (blockIdx.x << 2) | w;   // tile id = b*64 + t
    const int b    = g >> 6;

    float* tl = tile[w];

    // ---- stage tile into LDS, float4 coalesced, 16B-unit XOR swizzle ----
    {
        const float4* src4 = (const float4*)(seg_emb + (size_t)g * 4096);
        float4* tl4 = (float4*)tl;
        #pragma unroll
        for (int i = 0; i < 16; ++i) {
            int q = (i << 6) | lane;          // float4 index 0..1023
            float4 v = src4[q];
            int s = q >> 4, u = q & 15;
            tl4[(s << 4) | (u ^ (s & 7))] = v;
        }
    }

    // ---- early mask load: HBM latency hides under the GEMM phase ----
    const int s = lane;
    const int mval = smask[(g << 6) | s];

    __syncthreads();

    // ---- GEMM: lane <-> s, 64 j-accumulators in registers ----
    float acc[64];
    {
        const float* pr = posc + s * 64;      // per-lane row
        const float* tr = tgtc + b * 64;      // wave-uniform -> s_load
        #pragma unroll
        for (int j = 0; j < 64; ++j) acc[j] = pr[j] + tr[j];
    }
    const float4* tl4 = (const float4*)tl;
    const int sw = s & 7;
    float4 a = tl4[(s << 4) | (0 ^ sw)];      // prologue: prefetch dc=0
    #pragma unroll 1
    for (int dc = 0; dc < 15; ++dc) {
        float4 nxt = tl4[(s << 4) | ((dc + 1) ^ sw)];   // prefetch dc+1
        const float* w0 = att_w1 + (dc << 8); // 4 rows of w_emb, uniform -> s_load
        #pragma unroll
        for (int j = 0; j < 64; ++j) {
            float t0 = fmaf(a.w, w0[192 + j], acc[j]);
            t0 = fmaf(a.z, w0[128 + j], t0);
            t0 = fmaf(a.y, w0[64 + j], t0);
            acc[j] = fmaf(a.x, w0[j], t0);
        }
        a = nxt;
    }
    {   // epilogue: dc = 15
        const float* w0 = att_w1 + (15 << 8);
        #pragma unroll
        for (int j = 0; j < 64; ++j) {
            float t0 = fmaf(a.w, w0[192 + j], acc[j]);
            t0 = fmaf(a.z, w0[128 + j], t0);
            t0 = fmaf(a.y, w0[64 + j], t0);
            acc[j] = fmaf(a.x, w0[j], t0);
        }
    }

    // ---- score = relu(h) . att_w2 + b2, mask, wave softmax ----
    float sc = att_b2[0];
    #pragma unroll
    for (int j = 0; j < 64; ++j) sc = fmaf(fmaxf(acc[j], 0.0f), att_w2[j], sc);
    if (mval == 0) sc = NEG_INF;

    float mx = sc;
    #pragma unroll
    for (int off = 32; off; off >>= 1) mx = fmaxf(mx, __shfl_xor(mx, off));
    float e = __expf(sc - mx);
    float sum = e;
    #pragma unroll
    for (int off = 32; off; off >>= 1) sum += __shfl_xor(sum, off);
    attn_s[w][lane] = e / sum;
    __syncthreads();

    // ---- weighted sum over s: lane <-> d ----
    const int d = lane;
    float segv = 0.0f;
    #pragma unroll
    for (int s2 = 0; s2 < 64; ++s2) {
        float av = attn_s[w][s2];             // LDS broadcast
        float tv = tl[(s2 << 6) | ((((d >> 2) ^ (s2 & 7)) << 2) | (d & 3))];
        segv = fmaf(av, tv, segv);
    }
    segv_s[w][d] = segv;
    __syncthreads();

    // ---- projection + layernorm (lane <-> d') ----
    float o = proj_b[d];
    #pragma unroll
    for (int d2 = 0; d2 < 64; ++d2)
        o = fmaf(segv_s[w][d2], proj_w[(d2 << 6) | d], o);

    float ssum = o;
    #pragma unroll
    for (int off = 32; off; off >>= 1) ssum += __shfl_xor(ssum, off);
    float mu = ssum * (1.0f / 64.0f);
    float df = o - mu;
    float vsum = df * df;
    #pragma unroll
    for (int off = 32; off; off >>= 1) vsum += __shfl_xor(vsum, off);
    float var = vsum * (1.0f / 64.0f);
    float inv = 1.0f / sqrtf(var + 1e-5f);
    out[(g << 6) | d] = fmaf(df * inv, ln_g[d], ln_b[d]);
}

extern "C" void kernel_launch(void* const* d_in, const int* in_sizes, int n_in,
                              void* d_out, int out_size, void* d_ws, size_t ws_size,
                              hipStream_t stream)
{
    const float* seg_emb    = (const float*)d_in[0];
    const int*   smask      = (const int*)  d_in[1];
    const float* target_emb = (const float*)d_in[2];
    const float* pos_w1     = (const float*)d_in[3];
    const float* pos_b1     = (const float*)d_in[4];
    const float* pos_w2     = (const float*)d_in[5];
    const float* pos_b2     = (const float*)d_in[6];
    const float* att_w1     = (const float*)d_in[7];
    const float* att_b1     = (const float*)d_in[8];
    const float* att_w2     = (const float*)d_in[9];
    const float* att_b2     = (const float*)d_in[10];
    const float* proj_w     = (const float*)d_in[11];
    const float* proj_b     = (const float*)d_in[12];
    const float* ln_g       = (const float*)d_in[13];
    const float* ln_b       = (const float*)d_in[14];
    float* out = (float*)d_out;

    float* posc = (float*)d_ws;        // 4096 floats
    float* tgtc = posc + 4096;         // 8192 floats

    doe_pre_kernel<<<192, 64, 0, stream>>>(pos_w1, pos_b1, pos_w2, pos_b2,
                                           att_w1, att_b1, target_emb, posc, tgtc);
    doe_main_kernel<<<2048, 256, 0, stream>>>(seg_emb, smask, att_w1, att_w2,
                                              att_b2, proj_w, proj_b, ln_g, ln_b,
                                              posc, tgtc, out);
}

// Round 6
// 263.224 us; speedup vs baseline: 1.0799x; 1.0799x over previous
//
#include <hip/hip_runtime.h>
#include <math.h>

#define NEG_INF -1000000000.0f

// ---------------------------------------------------------------------------
// Precompute kernel: blocks 0..63 -> posc[s][j] = (pos MLP @ w_pos) + att_b1
//                    blocks 64..191 -> tgtc[b][j] = target_emb[b] @ w_tgt
// ---------------------------------------------------------------------------
__global__ __launch_bounds__(64) void doe_pre_kernel(
    const float* __restrict__ pos_w1, const float* __restrict__ pos_b1,
    const float* __restrict__ pos_w2, const float* __restrict__ pos_b2,
    const float* __restrict__ att_w1, const float* __restrict__ att_b1,
    const float* __restrict__ target_emb,
    float* __restrict__ posc, float* __restrict__ tgtc)
{
    const int tid = threadIdx.x;
    if (blockIdx.x < 64) {
        const int s = blockIdx.x;
        __shared__ float p1[64];
        __shared__ float pe[64];
        float pos = (float)s * (1.0f / 63.0f);
        p1[tid] = fmaxf(fmaf(pos, pos_w1[tid], pos_b1[tid]), 0.0f);
        __syncthreads();
        float acc = pos_b2[tid];
        #pragma unroll
        for (int h = 0; h < 64; ++h) acc = fmaf(p1[h], pos_w2[h * 64 + tid], acc);
        pe[tid] = acc;
        __syncthreads();
        float pc = att_b1[tid];
        #pragma unroll
        for (int h = 0; h < 64; ++h) pc = fmaf(pe[h], att_w1[(64 + h) * 64 + tid], pc);
        posc[s * 64 + tid] = pc;
    } else {
        const int b = blockIdx.x - 64;
        const float* trow = target_emb + b * 64;   // wave-uniform -> s_load
        float acc = 0.0f;
        #pragma unroll
        for (int d = 0; d < 64; ++d) acc = fmaf(trow[d], att_w1[(128 + d) * 64 + tid], acc);
        tgtc[b * 64 + tid] = acc;
    }
}

// ---------------------------------------------------------------------------
// Main fused kernel, v2: ZERO LDS, zero barriers. One wave per (b,t) tile.
// R5 evidence: v1 (LDS-staged, 66KiB/block) was latency-bound: dur 123.6us,
// VALUBusy 32.7%, Occupancy 21.5% (2 waves/SIMD). Fix: drop LDS -> 16
// waves/CU; GEMM reads own row global->reg (depth-4 prefetch); the s<->d
// transpose uses coalesced COLUMN re-reads from L2 + __shfl broadcasts.
// ---------------------------------------------------------------------------
__device__ __forceinline__ void fma4rows(float acc[64], const float4 a,
                                         const float* __restrict__ w0)
{
    #pragma unroll
    for (int j = 0; j < 64; ++j) {
        float t0 = fmaf(a.w, w0[192 + j], acc[j]);
        t0 = fmaf(a.z, w0[128 + j], t0);
        t0 = fmaf(a.y, w0[64 + j], t0);
        acc[j] = fmaf(a.x, w0[j], t0);
    }
}

__global__ __launch_bounds__(256, 4) void doe_main_kernel(
    const float* __restrict__ seg_emb, const int* __restrict__ smask,
    const float* __restrict__ att_w1, const float* __restrict__ att_w2,
    const float* __restrict__ att_b2, const float* __restrict__ proj_w,
    const float* __restrict__ proj_b, const float* __restrict__ ln_g,
    const float* __restrict__ ln_b, const float* __restrict__ posc,
    const float* __restrict__ tgtc, float* __restrict__ out)
{
    const int w    = threadIdx.x >> 6;
    const int lane = threadIdx.x & 63;
    const int g    = (blockIdx.x << 2) | w;   // tile id = b*64 + t
    const int b    = g >> 6;
    const int s    = lane;

    // ---- issue first row-chunk loads early (lane's own row, 256 B) ----
    const float4* rp4 = (const float4*)(seg_emb + (size_t)g * 4096 + s * 64);
    float4 c0 = rp4[0], c1 = rp4[1], c2 = rp4[2], c3 = rp4[3];

    // ---- mask early: latency hides under acc init + GEMM ----
    const int mval = smask[(g << 6) | s];

    // ---- acc init: posc row (L2-resident) + tgtc (wave-uniform s_load) ----
    float acc[64];
    {
        const float4* pp4 = (const float4*)(posc + s * 64);
        const float*  tr  = tgtc + b * 64;
        #pragma unroll
        for (int jq = 0; jq < 16; ++jq) {
            float4 pv = pp4[jq];
            acc[4 * jq + 0] = pv.x + tr[4 * jq + 0];
            acc[4 * jq + 1] = pv.y + tr[4 * jq + 1];
            acc[4 * jq + 2] = pv.z + tr[4 * jq + 2];
            acc[4 * jq + 3] = pv.w + tr[4 * jq + 3];
        }
    }

    // ---- GEMM: 16 d-chunks, groups of 4, depth-4 register prefetch ----
    #pragma unroll 1
    for (int dq = 0; dq < 3; ++dq) {
        float4 n0 = rp4[4 * dq + 4], n1 = rp4[4 * dq + 5];
        float4 n2 = rp4[4 * dq + 6], n3 = rp4[4 * dq + 7];
        const float* wq = att_w1 + dq * 1024;  // wave-uniform -> s_load
        fma4rows(acc, c0, wq);
        fma4rows(acc, c1, wq + 256);
        fma4rows(acc, c2, wq + 512);
        fma4rows(acc, c3, wq + 768);
        c0 = n0; c1 = n1; c2 = n2; c3 = n3;
    }
    {   // epilogue dq = 3
        const float* wq = att_w1 + 3 * 1024;
        fma4rows(acc, c0, wq);
        fma4rows(acc, c1, wq + 256);
        fma4rows(acc, c2, wq + 512);
        fma4rows(acc, c3, wq + 768);
    }

    // ---- score = relu(h) . att_w2 + b2, mask ----
    float sc = att_b2[0];
    #pragma unroll
    for (int j = 0; j < 64; ++j) sc = fmaf(fmaxf(acc[j], 0.0f), att_w2[j], sc);
    if (mval == 0) sc = NEG_INF;

    // ---- wave softmax (all-masked row -> uniform 1/64, matches jax) ----
    float mx = sc;
    #pragma unroll
    for (int off = 32; off; off >>= 1) mx = fmaxf(mx, __shfl_xor(mx, off));
    float e = __expf(sc - mx);
    float sum = e;
    #pragma unroll
    for (int off = 32; off; off >>= 1) sum += __shfl_xor(sum, off);
    const float p = e / sum;                  // attn weight for row s=lane

    // ---- weighted sum over s: coalesced column re-reads (L2-hot tile) ----
    const float* colb = seg_emb + (size_t)g * 4096 + lane;   // d = lane
    float segv = 0.0f;
    #pragma unroll
    for (int s2 = 0; s2 < 64; ++s2) {
        float av = __shfl(p, s2);             // broadcast attn[s2]
        segv = fmaf(av, colb[s2 * 64], segv);
    }

    // ---- projection: segv broadcast + coalesced proj_w rows ----
    float o = proj_b[lane];
    #pragma unroll
    for (int d2 = 0; d2 < 64; ++d2) {
        float sv = __shfl(segv, d2);
        o = fmaf(sv, proj_w[d2 * 64 + lane], o);
    }

    // ---- layernorm ----
    float ssum = o;
    #pragma unroll
    for (int off = 32; off; off >>= 1) ssum += __shfl_xor(ssum, off);
    float mu = ssum * (1.0f / 64.0f);
    float df = o - mu;
    float vsum = df * df;
    #pragma unroll
    for (int off = 32; off; off >>= 1) vsum += __shfl_xor(vsum, off);
    float var = vsum * (1.0f / 64.0f);
    float inv = 1.0f / sqrtf(var + 1e-5f);
    out[(g << 6) | lane] = fmaf(df * inv, ln_g[lane], ln_b[lane]);
}

extern "C" void kernel_launch(void* const* d_in, const int* in_sizes, int n_in,
                              void* d_out, int out_size, void* d_ws, size_t ws_size,
                              hipStream_t stream)
{
    const float* seg_emb    = (const float*)d_in[0];
    const int*   smask      = (const int*)  d_in[1];
    const float* target_emb = (const float*)d_in[2];
    const float* pos_w1     = (const float*)d_in[3];
    const float* pos_b1     = (const float*)d_in[4];
    const float* pos_w2     = (const float*)d_in[5];
    const float* pos_b2     = (const float*)d_in[6];
    const float* att_w1     = (const float*)d_in[7];
    const float* att_b1     = (const float*)d_in[8];
    const float* att_w2     = (const float*)d_in[9];
    const float* att_b2     = (const float*)d_in[10];
    const float* proj_w     = (const float*)d_in[11];
    const float* proj_b     = (const float*)d_in[12];
    const float* ln_g       = (const float*)d_in[13];
    const float* ln_b       = (const float*)d_in[14];
    float* out = (float*)d_out;

    float* posc = (float*)d_ws;        // 4096 floats
    float* tgtc = posc + 4096;         // 8192 floats

    doe_pre_kernel<<<192, 64, 0, stream>>>(pos_w1, pos_b1, pos_w2, pos_b2,
                                           att_w1, att_b1, target_emb, posc, tgtc);
    doe_main_kernel<<<2048, 256, 0, stream>>>(seg_emb, smask, att_w1, att_w2,
                                              att_b2, proj_w, proj_b, ln_g, ln_b,
                                              posc, tgtc, out);
}